// Round 11
// baseline (109.351 us; speedup 1.0000x reference)
//
#include <hip/hip_runtime.h>
#include <hip/hip_fp16.h>
#include <cstdint>
#include <cstddef>

// z = soft_thresh(Toeplitz(v) @ x + W2 @ y, beta) -- complex, N=1024, M=256, B=1024
// Output = Re(z) only: [1024,1024] f32.
//
// R29 = R27 (best, 105.4us) with fft_conv batching 2 COLUMNS PER THREAD:
// every __sincosf twiddle (~72/thread), every g_V load, and all index math
// now serve 2 columns (per-column fixed VALU halves). Exchange keeps R27's
// dbuf + PHYS pad; per exchange point: write e0->ex[0], sync, read e0 +
// write e1->ex[1], sync, read e1 (8 barriers, 2-wave blocks -> cheap).
// LDS 34.8KB unchanged -> 4 blocks/CU, 8 waves/CU. Grid 512 blocks.
// R28 post-mortem: table twiddles + single-buffer regressed (+2.4us) ->
// reverted; sincosf + dbuf re-validated. build_all/gemm_w2y = R27 verbatim.

#define BETA_F 0.01f
#define EPS_F  1e-12f
#define TWN 3.0679615757712823e-3f    // 2*pi/2048

typedef __attribute__((ext_vector_type(8))) _Float16 half8;
typedef __attribute__((ext_vector_type(4))) _Float16 half4;
typedef __attribute__((ext_vector_type(4))) float   floatx4;

__device__ alignas(16) _Float16 g_A2[1024 * 512];        // 1 MB  [W2_re | W2_im]
__device__ alignas(16) _Float16 g_B2t[2048 * 512];       // 2 MB  [y embedding]^T
__device__ alignas(16) float2   g_xT[1024 * 1024];       // 8 MB  xT[b][n]
__device__ alignas(16) float2   g_V[2048];               // FFT(u~)/2048, bitrev order
__device__ alignas(16) float2   g_convT[1024 * 1024];    // 8 MB  conv^T[b][i]

// ---------------- prep: A2', B2t, xT, V (unchanged, passed) ------------------
__global__ __launch_bounds__(256) void build_all(
    const float* __restrict__ v_re, const float* __restrict__ v_im,
    const float* __restrict__ W2_re, const float* __restrict__ W2_im,
    const float* __restrict__ x_re, const float* __restrict__ x_im,
    const float* __restrict__ y_re, const float* __restrict__ y_im)
{
    __shared__ __align__(16) char sbuf[24576];
    const int bx  = blockIdx.x;
    const int tid = threadIdx.x;

    if (bx < 256) {                            // ---- A2'[1024][512] fp16
        int t  = bx * 256 + tid;
        int i  = t >> 6;
        int kp = (t & 63) * 8;
        half8 h;
        if (kp < 256) {
            const float* s = W2_re + i * 256 + kp;
#pragma unroll
            for (int j = 0; j < 8; ++j) h[j] = (_Float16)s[j];
        } else {
            const float* s = W2_im + i * 256 + (kp - 256);
#pragma unroll
            for (int j = 0; j < 8; ++j) h[j] = (_Float16)s[j];
        }
        *reinterpret_cast<half8*>(g_A2 + (size_t)i * 512 + kp) = h;
        return;
    }
    if (bx < 512) {                            // ---- B2t[2048][512] fp16 (y^T)
        float (*lre)[33] = (float(*)[33])sbuf;
        float (*lim)[33] = (float(*)[33])(sbuf + 4224);
        int idx = bx - 256;
        int bk  = idx & 7;
        int by  = idx >> 3;
        int k0  = bk * 32;
        int n0  = by * 32;
        {
            int kk  = tid >> 3;
            int tx4 = (tid & 7) * 4;
            const floatx4 re4 = *reinterpret_cast<const floatx4*>(
                y_re + (size_t)(k0 + kk) * 1024 + n0 + tx4);
            const floatx4 im4 = *reinterpret_cast<const floatx4*>(
                y_im + (size_t)(k0 + kk) * 1024 + n0 + tx4);
#pragma unroll
            for (int j = 0; j < 4; ++j) {
                lre[kk][tx4 + j] = re4[j];
                lim[kk][tx4 + j] = im4[j];
            }
        }
        __syncthreads();
        int lane_n = tid >> 3;
        int kq     = (tid & 7) * 4;
        half4 hre, him, hmim;
#pragma unroll
        for (int j = 0; j < 4; ++j) {
            float re = lre[kq + j][lane_n];
            float im = lim[kq + j][lane_n];
            hre[j]  = (_Float16)re;
            him[j]  = (_Float16)im;
            hmim[j] = (_Float16)(-im);
        }
        int n = n0 + lane_n;
        _Float16* r0 = g_B2t + (size_t)(2 * n)     * 512;
        _Float16* r1 = g_B2t + (size_t)(2 * n + 1) * 512;
        *reinterpret_cast<half4*>(r0 + k0 + kq)       = hre;
        *reinterpret_cast<half4*>(r0 + 256 + k0 + kq) = hmim;
        *reinterpret_cast<half4*>(r1 + k0 + kq)       = him;
        *reinterpret_cast<half4*>(r1 + 256 + k0 + kq) = hre;
        return;
    }
    if (bx < 1536) {                           // ---- xT[b][n] float2 (x^T)
        float (*lre)[33] = (float(*)[33])sbuf;
        float (*lim)[33] = (float(*)[33])(sbuf + 4224);
        int idx = bx - 512;
        int n0  = (idx >> 5) * 32;
        int b0  = (idx & 31) * 32;
        {
            int kk  = tid >> 3;
            int tx4 = (tid & 7) * 4;
            const floatx4 re4 = *reinterpret_cast<const floatx4*>(
                x_re + (size_t)(n0 + kk) * 1024 + b0 + tx4);
            const floatx4 im4 = *reinterpret_cast<const floatx4*>(
                x_im + (size_t)(n0 + kk) * 1024 + b0 + tx4);
#pragma unroll
            for (int j = 0; j < 4; ++j) {
                lre[kk][tx4 + j] = re4[j];
                lim[kk][tx4 + j] = im4[j];
            }
        }
        __syncthreads();
        int bb  = tid >> 3;
        int nn4 = (tid & 7) * 4;
        float2* dst = g_xT + (size_t)(b0 + bb) * 1024 + n0 + nn4;
        floatx4 w0, w1;
        w0[0] = lre[nn4 + 0][bb]; w0[1] = lim[nn4 + 0][bb];
        w0[2] = lre[nn4 + 1][bb]; w0[3] = lim[nn4 + 1][bb];
        w1[0] = lre[nn4 + 2][bb]; w1[1] = lim[nn4 + 2][bb];
        w1[2] = lre[nn4 + 3][bb]; w1[3] = lim[nn4 + 3][bb];
        *reinterpret_cast<floatx4*>(dst)     = w0;
        *reinterpret_cast<floatx4*>(dst + 2) = w1;
        return;
    }
    // ---- bx == 1536: V = DIF-FFT_2048(u~) * (1/2048), bit-reversed order ----
    float2* du = (float2*)sbuf;
    float*  twr = (float*)(sbuf + 16384);
    float*  twi = (float*)(sbuf + 20480);
#pragma unroll
    for (int r = 0; r < 4; ++r) {
        int k = tid + 256 * r;
        float ang = (float)k * TWN;
        float s, c;
        __sincosf(ang, &s, &c);
        twr[k] = c; twi[k] = -s;
    }
#pragma unroll
    for (int r = 0; r < 8; ++r) {
        int k = tid + 256 * r;
        float2 val;
        if (k < 1024)      { val.x = v_re[1023 + k]; val.y = v_im[1023 + k]; }
        else if (k == 1024){ val.x = 0.f; val.y = 0.f; }
        else               { val.x = v_re[k - 1025]; val.y = v_im[k - 1025]; }
        du[k] = val;
    }
    for (int s = 0; s < 11; ++s) {
        int lh = 10 - s, h = 1 << lh;
        __syncthreads();
#pragma unroll
        for (int r = 0; r < 4; ++r) {
            int i  = tid + 256 * r;
            int j  = i & (h - 1);
            int i0 = ((i >> lh) << (lh + 1)) | j;
            int i1 = i0 + h;
            float2 a = du[i0], b = du[i1];
            float dx = a.x - b.x, dy = a.y - b.y;
            int ti = j << s;
            float wr = twr[ti], wi = twi[ti];
            float2 s0; s0.x = a.x + b.x; s0.y = a.y + b.y;
            float2 d0; d0.x = dx * wr - dy * wi; d0.y = dx * wi + dy * wr;
            du[i0] = s0; du[i1] = d0;
        }
    }
    __syncthreads();
#pragma unroll
    for (int r = 0; r < 8; ++r) {
        int k = tid + 256 * r;
        float2 v = du[k];
        v.x *= (1.0f / 2048.0f); v.y *= (1.0f / 2048.0f);
        g_V[k] = v;
    }
}

// ---------------- FFT convolution v5: register-resident, 2 columns/thread ----
// 512 blocks x 128 thr, 2 columns each (e0, e1). Twiddles (sincosf), V loads,
// and index math shared across both columns. Exchange: R27 dbuf + PHYS pad;
// per exchange point 2 barriers (e0 via ex[0], e1 via ex[1]). 34.8KB LDS.
#define PHYS(L) ((L) + ((L) >> 4))
__global__ __launch_bounds__(128) void fft_conv()
{
    __shared__ float2 ex[2][2176];     // PHYS(2047)=2174; 34.8KB

    const int t  = threadIdx.x;        // 0..127
    const int c0 = blockIdx.x * 2;     // columns c0, c0+1
    const int q = t >> 3, u = t & 7;

    float2 e0[16], e1[16];

    auto tw = [](int expo) {
        float sn, cs;
        __sincosf((float)expo * TWN, &sn, &cs);
        float2 w; w.x = cs; w.y = -sn;      // W^expo
        return w;
    };
    auto fwd = [](float2& A, float2& B, float2 w) {
        float2 a = A, c = B;
        float dx = a.x - c.x, dy = a.y - c.y;
        A.x = a.x + c.x; A.y = a.y + c.y;
        B.x = dx * w.x - dy * w.y;
        B.y = dx * w.y + dy * w.x;
    };
    auto inv = [](float2& A, float2& B, float2 w) {
        float2 a = A, c = B;                // t1 = c * conj(w)
        float tx = c.x * w.x + c.y * w.y;
        float ty = c.y * w.x - c.x * w.y;
        A.x = a.x + tx; A.y = a.y + ty;
        B.x = a.x - tx; B.y = a.y - ty;
    };

    // ---- load L0 (both columns); upper halves zero ----
    const float2* s0 = g_xT + (size_t)c0 * 1024;
    const float2* s1 = s0 + 1024;
#pragma unroll
    for (int r = 0; r < 8; ++r) { e0[r] = s0[t + 128 * r]; e1[r] = s1[t + 128 * r]; }
#pragma unroll
    for (int r = 8; r < 16; ++r) {
        e0[r].x = 0.f; e0[r].y = 0.f;
        e1[r].x = 0.f; e1[r].y = 0.f;
    }

    // ---- forward s=0..3 (register-local in L0) ----
#pragma unroll
    for (int r = 0; r < 8; ++r) {                                              // s=0
        float2 w = tw(t + 128 * r);
        fwd(e0[r], e0[r + 8], w); fwd(e1[r], e1[r + 8], w);
    }
#pragma unroll
    for (int r0 = 0; r0 < 4; ++r0) {                                           // s=1
        float2 w = tw((t + 128 * r0) << 1);
        fwd(e0[r0], e0[r0 + 4], w); fwd(e0[r0 + 8], e0[r0 + 12], w);
        fwd(e1[r0], e1[r0 + 4], w); fwd(e1[r0 + 8], e1[r0 + 12], w);
    }
#pragma unroll
    for (int r0 = 0; r0 < 2; ++r0) {                                           // s=2
        float2 w = tw((t + 128 * r0) << 2);
#pragma unroll
        for (int g4 = 0; g4 < 4; ++g4) {
            fwd(e0[g4 * 4 + r0], e0[g4 * 4 + r0 + 2], w);
            fwd(e1[g4 * 4 + r0], e1[g4 * 4 + r0 + 2], w);
        }
    }
    {                                                                          // s=3
        float2 w = tw(t << 3);
#pragma unroll
        for (int g2 = 0; g2 < 8; ++g2) {
            fwd(e0[g2 * 2], e0[g2 * 2 + 1], w);
            fwd(e1[g2 * 2], e1[g2 * 2 + 1], w);
        }
    }

    // ---- exchange 1: L0 -> L1 (f[k] = x[128 q + u + 8 k]) ----
#pragma unroll
    for (int r = 0; r < 16; ++r) ex[0][PHYS(128 * r + t)] = e0[r];
    __syncthreads();
#pragma unroll
    for (int k = 0; k < 16; ++k) e0[k] = ex[0][PHYS(128 * q + u + 8 * k)];
#pragma unroll
    for (int r = 0; r < 16; ++r) ex[1][PHYS(128 * r + t)] = e1[r];
    __syncthreads();
#pragma unroll
    for (int k = 0; k < 16; ++k) e1[k] = ex[1][PHYS(128 * q + u + 8 * k)];

    // ---- forward s=4..7 (register-local in L1) ----
#pragma unroll
    for (int k = 0; k < 8; ++k) {                                              // s=4
        float2 w = tw((u + 8 * k) << 4);
        fwd(e0[k], e0[k + 8], w); fwd(e1[k], e1[k + 8], w);
    }
#pragma unroll
    for (int k0 = 0; k0 < 4; ++k0) {                                           // s=5
        float2 w = tw((u + 8 * k0) << 5);
        fwd(e0[k0], e0[k0 + 4], w); fwd(e0[k0 + 8], e0[k0 + 12], w);
        fwd(e1[k0], e1[k0 + 4], w); fwd(e1[k0 + 8], e1[k0 + 12], w);
    }
#pragma unroll
    for (int k0 = 0; k0 < 2; ++k0) {                                           // s=6
        float2 w = tw((u + 8 * k0) << 6);
#pragma unroll
        for (int g4 = 0; g4 < 4; ++g4) {
            fwd(e0[g4 * 4 + k0], e0[g4 * 4 + k0 + 2], w);
            fwd(e1[g4 * 4 + k0], e1[g4 * 4 + k0 + 2], w);
        }
    }
    {                                                                          // s=7
        float2 w = tw(u << 7);
#pragma unroll
        for (int g2 = 0; g2 < 8; ++g2) {
            fwd(e0[g2 * 2], e0[g2 * 2 + 1], w);
            fwd(e1[g2 * 2], e1[g2 * 2 + 1], w);
        }
    }

    // ---- exchange 2: L1 -> L2 (g[k] = x[16 t + k]) ----
#pragma unroll
    for (int k = 0; k < 16; ++k) ex[0][PHYS(128 * q + u + 8 * k)] = e0[k];
    __syncthreads();
#pragma unroll
    for (int k = 0; k < 16; ++k) e0[k] = ex[0][PHYS(16 * t + k)];
#pragma unroll
    for (int k = 0; k < 16; ++k) ex[1][PHYS(128 * q + u + 8 * k)] = e1[k];
    __syncthreads();
#pragma unroll
    for (int k = 0; k < 16; ++k) e1[k] = ex[1][PHYS(16 * t + k)];

    // ---- forward s=8..10 (register-local in L2) ----
#pragma unroll
    for (int c = 0; c < 4; ++c) {                                              // s=8
        float2 w = tw(c << 8);
        fwd(e0[c], e0[c + 4], w); fwd(e0[c + 8], e0[c + 12], w);
        fwd(e1[c], e1[c + 4], w); fwd(e1[c + 8], e1[c + 12], w);
    }
#pragma unroll
    for (int g4 = 0; g4 < 4; ++g4) {                                           // s=9
        fwd(e0[g4 * 4], e0[g4 * 4 + 2], (float2){1.f, 0.f});
        fwd(e1[g4 * 4], e1[g4 * 4 + 2], (float2){1.f, 0.f});
        {   // c=1: w=(0,-1) -> d*w = (dy,-dx)
            float2& A = e0[g4 * 4 + 1]; float2& B = e0[g4 * 4 + 3];
            float2 a = A, c2 = B;
            float dx = a.x - c2.x, dy = a.y - c2.y;
            A.x = a.x + c2.x; A.y = a.y + c2.y;
            B.x = dy; B.y = -dx;
        }
        {
            float2& A = e1[g4 * 4 + 1]; float2& B = e1[g4 * 4 + 3];
            float2 a = A, c2 = B;
            float dx = a.x - c2.x, dy = a.y - c2.y;
            A.x = a.x + c2.x; A.y = a.y + c2.y;
            B.x = dy; B.y = -dx;
        }
    }
#pragma unroll
    for (int g2 = 0; g2 < 8; ++g2) {                                           // s=10
        {
            float2 a = e0[g2 * 2], c2 = e0[g2 * 2 + 1];
            e0[g2 * 2].x     = a.x + c2.x; e0[g2 * 2].y     = a.y + c2.y;
            e0[g2 * 2 + 1].x = a.x - c2.x; e0[g2 * 2 + 1].y = a.y - c2.y;
        }
        {
            float2 a = e1[g2 * 2], c2 = e1[g2 * 2 + 1];
            e1[g2 * 2].x     = a.x + c2.x; e1[g2 * 2].y     = a.y + c2.y;
            e1[g2 * 2 + 1].x = a.x - c2.x; e1[g2 * 2 + 1].y = a.y - c2.y;
        }
    }

    // ---- pointwise * V (bitrev domain; V pre-scaled); one load, two uses ----
#pragma unroll
    for (int k = 0; k < 16; ++k) {
        float2 v = g_V[16 * t + k];
        float2 a = e0[k];
        e0[k].x = a.x * v.x - a.y * v.y;
        e0[k].y = a.x * v.y + a.y * v.x;
        float2 b = e1[k];
        e1[k].x = b.x * v.x - b.y * v.y;
        e1[k].y = b.x * v.y + b.y * v.x;
    }

    // ---- inverse ss=0..2 (register-local in L2) ----
#pragma unroll
    for (int g2 = 0; g2 < 8; ++g2) {                                           // ss=0
        {
            float2 a = e0[g2 * 2], c2 = e0[g2 * 2 + 1];
            e0[g2 * 2].x     = a.x + c2.x; e0[g2 * 2].y     = a.y + c2.y;
            e0[g2 * 2 + 1].x = a.x - c2.x; e0[g2 * 2 + 1].y = a.y - c2.y;
        }
        {
            float2 a = e1[g2 * 2], c2 = e1[g2 * 2 + 1];
            e1[g2 * 2].x     = a.x + c2.x; e1[g2 * 2].y     = a.y + c2.y;
            e1[g2 * 2 + 1].x = a.x - c2.x; e1[g2 * 2 + 1].y = a.y - c2.y;
        }
    }
#pragma unroll
    for (int g4 = 0; g4 < 4; ++g4) {                                           // ss=1
        inv(e0[g4 * 4], e0[g4 * 4 + 2], (float2){1.f, 0.f});
        inv(e1[g4 * 4], e1[g4 * 4 + 2], (float2){1.f, 0.f});
        {   // c=1: t1 = c*conj(0,-1) = (-c.y, c.x)
            float2& A = e0[g4 * 4 + 1]; float2& B = e0[g4 * 4 + 3];
            float2 a = A, c2 = B;
            float tx = -c2.y, ty = c2.x;
            A.x = a.x + tx; A.y = a.y + ty;
            B.x = a.x - tx; B.y = a.y - ty;
        }
        {
            float2& A = e1[g4 * 4 + 1]; float2& B = e1[g4 * 4 + 3];
            float2 a = A, c2 = B;
            float tx = -c2.y, ty = c2.x;
            A.x = a.x + tx; A.y = a.y + ty;
            B.x = a.x - tx; B.y = a.y - ty;
        }
    }
#pragma unroll
    for (int c = 0; c < 4; ++c) {                                              // ss=2
        float2 w = tw(c << 8);
        inv(e0[c], e0[c + 4], w); inv(e0[c + 8], e0[c + 12], w);
        inv(e1[c], e1[c + 4], w); inv(e1[c + 8], e1[c + 12], w);
    }

    // ---- exchange 3: L2 -> L1 ----
#pragma unroll
    for (int k = 0; k < 16; ++k) ex[0][PHYS(16 * t + k)] = e0[k];
    __syncthreads();
#pragma unroll
    for (int k = 0; k < 16; ++k) e0[k] = ex[0][PHYS(128 * q + u + 8 * k)];
#pragma unroll
    for (int k = 0; k < 16; ++k) ex[1][PHYS(16 * t + k)] = e1[k];
    __syncthreads();
#pragma unroll
    for (int k = 0; k < 16; ++k) e1[k] = ex[1][PHYS(128 * q + u + 8 * k)];

    // ---- inverse ss=3..6 (register-local in L1) ----
    {                                                                          // ss=3
        float2 w = tw(u << 7);
#pragma unroll
        for (int g2 = 0; g2 < 8; ++g2) {
            inv(e0[g2 * 2], e0[g2 * 2 + 1], w);
            inv(e1[g2 * 2], e1[g2 * 2 + 1], w);
        }
    }
#pragma unroll
    for (int k0 = 0; k0 < 2; ++k0) {                                           // ss=4
        float2 w = tw((u + 8 * k0) << 6);
#pragma unroll
        for (int g4 = 0; g4 < 4; ++g4) {
            inv(e0[g4 * 4 + k0], e0[g4 * 4 + k0 + 2], w);
            inv(e1[g4 * 4 + k0], e1[g4 * 4 + k0 + 2], w);
        }
    }
#pragma unroll
    for (int k0 = 0; k0 < 4; ++k0) {                                           // ss=5
        float2 w = tw((u + 8 * k0) << 5);
        inv(e0[k0], e0[k0 + 4], w); inv(e0[k0 + 8], e0[k0 + 12], w);
        inv(e1[k0], e1[k0 + 4], w); inv(e1[k0 + 8], e1[k0 + 12], w);
    }
#pragma unroll
    for (int k = 0; k < 8; ++k) {                                              // ss=6
        float2 w = tw((u + 8 * k) << 4);
        inv(e0[k], e0[k + 8], w); inv(e1[k], e1[k + 8], w);
    }

    // ---- exchange 4: L1 -> L0 ----
#pragma unroll
    for (int k = 0; k < 16; ++k) ex[0][PHYS(128 * q + u + 8 * k)] = e0[k];
    __syncthreads();
#pragma unroll
    for (int r = 0; r < 16; ++r) e0[r] = ex[0][PHYS(128 * r + t)];
#pragma unroll
    for (int k = 0; k < 16; ++k) ex[1][PHYS(128 * q + u + 8 * k)] = e1[k];
    __syncthreads();
#pragma unroll
    for (int r = 0; r < 16; ++r) e1[r] = ex[1][PHYS(128 * r + t)];

    // ---- inverse ss=7..10 (register-local in L0) ----
    {                                                                          // ss=7
        float2 w = tw(t << 3);
#pragma unroll
        for (int g2 = 0; g2 < 8; ++g2) {
            inv(e0[g2 * 2], e0[g2 * 2 + 1], w);
            inv(e1[g2 * 2], e1[g2 * 2 + 1], w);
        }
    }
#pragma unroll
    for (int r0 = 0; r0 < 2; ++r0) {                                           // ss=8
        float2 w = tw((t + 128 * r0) << 2);
#pragma unroll
        for (int g4 = 0; g4 < 4; ++g4) {
            inv(e0[g4 * 4 + r0], e0[g4 * 4 + r0 + 2], w);
            inv(e1[g4 * 4 + r0], e1[g4 * 4 + r0 + 2], w);
        }
    }
#pragma unroll
    for (int r0 = 0; r0 < 4; ++r0) {                                           // ss=9
        float2 w = tw((t + 128 * r0) << 1);
        inv(e0[r0], e0[r0 + 4], w); inv(e0[r0 + 8], e0[r0 + 12], w);
        inv(e1[r0], e1[r0 + 4], w); inv(e1[r0 + 8], e1[r0 + 12], w);
    }
    // ss=10 folded into store (lower 1024 only), shared twiddle
    float2* d0 = g_convT + (size_t)c0 * 1024;
    float2* d1 = d0 + 1024;
#pragma unroll
    for (int r = 0; r < 8; ++r) {
        float2 w = tw(t + 128 * r);
        {
            float2 a = e0[r], c2 = e0[r + 8];
            float tx = c2.x * w.x + c2.y * w.y;
            float ty = c2.y * w.x - c2.x * w.y;
            float2 o; o.x = a.x + tx; o.y = a.y + ty;
            d0[t + 128 * r] = o;
        }
        {
            float2 a = e1[r], c2 = e1[r + 8];
            float tx = c2.x * w.x + c2.y * w.y;
            float ty = c2.y * w.x - c2.x * w.y;
            float2 o; o.x = a.x + tx; o.y = a.y + ty;
            d1[t + 128 * r] = o;
        }
    }
}

// ---------------- W2@y GEMM (K=512) + fused conv-add + soft-threshold --------
// R13 structure; epilogue LDS-stages the conv tile (unchanged from R27).
__global__ __launch_bounds__(256, 2) void gemm_w2y(float* __restrict__ out,
                                                   int out_n)
{
    __shared__ __align__(16) _Float16 As[2 * 4 * 64 * 32];
    __shared__ __align__(16) _Float16 Bs[2 * 4 * 64 * 32];

    const int tid  = threadIdx.x;
    const int lane = tid & 63;
    const int w    = tid >> 6;
    const int wm   = w >> 1;
    const int wn   = w & 1;

    const int bid = blockIdx.x;
    const int xcd = bid & 7;
    const int t   = bid >> 3;
    const int mi0 = ((xcd & 1) * 8 + (t & 7)) * 64;
    const int ni0 = ((xcd >> 1) * 8 + (t >> 3)) * 64;

    floatx4 acc[2][2];
#pragma unroll
    for (int a = 0; a < 2; ++a)
#pragma unroll
        for (int b = 0; b < 2; ++b) acc[a][b] = (floatx4)0.0f;

    const int rS = tid >> 2;
    const int jS = tid & 3;
    const int s0 = ((rS & 15) >> 1) & 3;
    char* asW = (char*)As + rS * 64 + ((jS ^ s0) * 16);
    char* bsW = (char*)Bs + rS * 64 + ((jS ^ s0) * 16);
    const _Float16* gA = g_A2  + (size_t)(mi0 + rS) * 512 + jS * 8;
    const _Float16* gB = g_B2t + (size_t)(ni0 + rS) * 512 + jS * 8;

    const int rowA = lane & 15;
    const int q    = lane >> 4;
    const int coff = (q ^ ((rowA >> 1) & 3)) * 16;

    const int NIT = 512 / 128;           // 4

    half8 sA[2][4], sB[2][4];
    {
        half8 tA[4], tB[4];
#pragma unroll
        for (int ks = 0; ks < 4; ++ks) {
            tA[ks] = *reinterpret_cast<const half8*>(gA + ks * 32);
            tB[ks] = *reinterpret_cast<const half8*>(gB + ks * 32);
        }
#pragma unroll
        for (int ks = 0; ks < 4; ++ks) {
            sA[1][ks] = *reinterpret_cast<const half8*>(gA + 128 + ks * 32);
            sB[1][ks] = *reinterpret_cast<const half8*>(gB + 128 + ks * 32);
        }
#pragma unroll
        for (int ks = 0; ks < 4; ++ks) {
            *reinterpret_cast<half8*>(asW + ks * 4096) = tA[ks];
            *reinterpret_cast<half8*>(bsW + ks * 4096) = tB[ks];
        }
    }
    __syncthreads();

#pragma unroll 2
    for (int kt = 0; kt < NIT; ++kt) {
        const int cur = kt & 1;
        const int nxt = cur ^ 1;
        if (kt + 2 < NIT) {
            const _Float16* ga = gA + (size_t)(kt + 2) * 128;
            const _Float16* gb = gB + (size_t)(kt + 2) * 128;
#pragma unroll
            for (int ks = 0; ks < 4; ++ks) {
                sA[cur][ks] = *reinterpret_cast<const half8*>(ga + ks * 32);
                sB[cur][ks] = *reinterpret_cast<const half8*>(gb + ks * 32);
            }
        }
        const char* Ab = (const char*)As + cur * 16384;
        const char* Bb = (const char*)Bs + cur * 16384;
#pragma unroll
        for (int ks = 0; ks < 4; ++ks) {
            half8 af[2], bf[2];
#pragma unroll
            for (int mi = 0; mi < 2; ++mi) {
                int r = wm * 32 + mi * 16 + rowA;
                af[mi] = *reinterpret_cast<const half8*>(Ab + ks * 4096 + r * 64 + coff);
            }
#pragma unroll
            for (int ni = 0; ni < 2; ++ni) {
                int r = wn * 32 + ni * 16 + rowA;
                bf[ni] = *reinterpret_cast<const half8*>(Bb + ks * 4096 + r * 64 + coff);
            }
#pragma unroll
            for (int mi = 0; mi < 2; ++mi)
#pragma unroll
                for (int ni = 0; ni < 2; ++ni)
                    acc[mi][ni] = __builtin_amdgcn_mfma_f32_16x16x32_f16(
                        af[mi], bf[ni], acc[mi][ni], 0, 0, 0);
        }
        if (kt + 1 < NIT) {
            char* aw = asW + nxt * 16384;
            char* bw = bsW + nxt * 16384;
#pragma unroll
            for (int ks = 0; ks < 4; ++ks) {
                *reinterpret_cast<half8*>(aw + ks * 4096) = sA[nxt][ks];
                *reinterpret_cast<half8*>(bw + ks * 4096) = sB[nxt][ks];
            }
        }
        __syncthreads();
    }

    // ---- stage conv tile (coalesced) into LDS: Lc[32][64], stride 66 --------
    float2* Lc = (float2*)As;            // K-loop done (barrier passed), As free
    {
        const int bl  = tid >> 3;        // 0..31
        const int il8 = (tid & 7) * 8;   // 0..56
        const float2* gsc = g_convT + (size_t)((ni0 >> 1) + bl) * 1024 + mi0 + il8;
#pragma unroll
        for (int j = 0; j < 8; j += 2) {
            floatx4 v = *reinterpret_cast<const floatx4*>(gsc + j);
            *reinterpret_cast<floatx4*>(Lc + bl * 66 + il8 + j) = v;
        }
    }
    __syncthreads();

    // epilogue: lane pair (even,odd) = (Re,Im); add conv, threshold, store Re.
    const int colL  = lane & 15;
    const int rquad = (lane >> 4) * 4;
#pragma unroll
    for (int mi = 0; mi < 2; ++mi)
#pragma unroll
        for (int ni = 0; ni < 2; ++ni)
#pragma unroll
            for (int r = 0; r < 4; ++r) {
                float c = acc[mi][ni][r];
                float p = __shfl_xor(c, 1, 64);
                if (!(colL & 1)) {
                    int bl2 = (wn * 32 + ni * 16 + colL) >> 1;   // 0..31
                    int il2 = wm * 32 + mi * 16 + rquad + r;     // 0..63
                    float2 cv = Lc[bl2 * 66 + il2];
                    float re = c + cv.x;
                    float im = p + cv.y;
                    float mag = sqrtf(re * re + im * im);
                    float s = fmaxf(mag - BETA_F, 0.0f) / fmaxf(mag, EPS_F);
                    int row  = mi0 + il2;
                    int bcol = (ni0 >> 1) + bl2;
                    size_t o = (size_t)row * 1024 + bcol;
                    if (o < (size_t)out_n) out[o] = re * s;
                }
            }
}

// ---------------- launcher ---------------------------------------------------
extern "C" void kernel_launch(void* const* d_in, const int* in_sizes, int n_in,
                              void* d_out, int out_size, void* d_ws, size_t ws_size,
                              hipStream_t stream) {
    (void)d_ws; (void)ws_size; (void)in_sizes; (void)n_in;
    const float* v_re  = (const float*)d_in[0];
    const float* v_im  = (const float*)d_in[1];
    const float* W2_re = (const float*)d_in[2];
    const float* W2_im = (const float*)d_in[3];
    const float* x_re  = (const float*)d_in[4];
    const float* x_im  = (const float*)d_in[5];
    const float* y_re  = (const float*)d_in[6];
    const float* y_im  = (const float*)d_in[7];
    float* out = (float*)d_out;

    build_all<<<1537, 256, 0, stream>>>(v_re, v_im, W2_re, W2_im,
                                        x_re, x_im, y_re, y_im);
    fft_conv<<<512, 128, 0, stream>>>();
    gemm_w2y<<<512, 256, 0, stream>>>(out, out_size);
}

// Round 12
// 107.583 us; speedup vs baseline: 1.0164x; 1.0164x over previous
//
#include <hip/hip_runtime.h>
#include <hip/hip_fp16.h>
#include <cstdint>
#include <cstddef>

// z = soft_thresh(Toeplitz(v) @ x + W2 @ y, beta) -- complex, N=1024, M=256, B=1024
// Output = Re(z) only: [1024,1024] f32.
//
// R30 = R27 resubmitted verbatim (session best: 105.4us).
// Ledger: R13-embedded-GEMM family plateau 107.2 (7 variants). FFT chain:
// R25 141 -> R26 112.3 -> R27 105.4 (register-resident FFT, 4 LDS round
// trips, sincosf twiddles, dbuf exchange) -> R28 107.8 (table+1buf, rev) ->
// R29 109.4 (2 col/thread, rev). R27 is the FFT-kernel local optimum from
// three directions; remaining budget is harness-fixed (poison fill ~43.5us,
// launch gaps) -> expect ~105.4, then declare roofline.

#define BETA_F 0.01f
#define EPS_F  1e-12f
#define TWN 3.0679615757712823e-3f    // 2*pi/2048

typedef __attribute__((ext_vector_type(8))) _Float16 half8;
typedef __attribute__((ext_vector_type(4))) _Float16 half4;
typedef __attribute__((ext_vector_type(4))) float   floatx4;

__device__ alignas(16) _Float16 g_A2[1024 * 512];        // 1 MB  [W2_re | W2_im]
__device__ alignas(16) _Float16 g_B2t[2048 * 512];       // 2 MB  [y embedding]^T
__device__ alignas(16) float2   g_xT[1024 * 1024];       // 8 MB  xT[b][n]
__device__ alignas(16) float2   g_V[2048];               // FFT(u~)/2048, bitrev order
__device__ alignas(16) float2   g_convT[1024 * 1024];    // 8 MB  conv^T[b][i]

// ---------------- prep: A2', B2t, xT, V --------------------------------------
__global__ __launch_bounds__(256) void build_all(
    const float* __restrict__ v_re, const float* __restrict__ v_im,
    const float* __restrict__ W2_re, const float* __restrict__ W2_im,
    const float* __restrict__ x_re, const float* __restrict__ x_im,
    const float* __restrict__ y_re, const float* __restrict__ y_im)
{
    __shared__ __align__(16) char sbuf[24576];
    const int bx  = blockIdx.x;
    const int tid = threadIdx.x;

    if (bx < 256) {                            // ---- A2'[1024][512] fp16
        int t  = bx * 256 + tid;
        int i  = t >> 6;
        int kp = (t & 63) * 8;
        half8 h;
        if (kp < 256) {
            const float* s = W2_re + i * 256 + kp;
#pragma unroll
            for (int j = 0; j < 8; ++j) h[j] = (_Float16)s[j];
        } else {
            const float* s = W2_im + i * 256 + (kp - 256);
#pragma unroll
            for (int j = 0; j < 8; ++j) h[j] = (_Float16)s[j];
        }
        *reinterpret_cast<half8*>(g_A2 + (size_t)i * 512 + kp) = h;
        return;
    }
    if (bx < 512) {                            // ---- B2t[2048][512] fp16 (y^T)
        float (*lre)[33] = (float(*)[33])sbuf;
        float (*lim)[33] = (float(*)[33])(sbuf + 4224);
        int idx = bx - 256;
        int bk  = idx & 7;
        int by  = idx >> 3;
        int k0  = bk * 32;
        int n0  = by * 32;
        {
            int kk  = tid >> 3;
            int tx4 = (tid & 7) * 4;
            const floatx4 re4 = *reinterpret_cast<const floatx4*>(
                y_re + (size_t)(k0 + kk) * 1024 + n0 + tx4);
            const floatx4 im4 = *reinterpret_cast<const floatx4*>(
                y_im + (size_t)(k0 + kk) * 1024 + n0 + tx4);
#pragma unroll
            for (int j = 0; j < 4; ++j) {
                lre[kk][tx4 + j] = re4[j];
                lim[kk][tx4 + j] = im4[j];
            }
        }
        __syncthreads();
        int lane_n = tid >> 3;
        int kq     = (tid & 7) * 4;
        half4 hre, him, hmim;
#pragma unroll
        for (int j = 0; j < 4; ++j) {
            float re = lre[kq + j][lane_n];
            float im = lim[kq + j][lane_n];
            hre[j]  = (_Float16)re;
            him[j]  = (_Float16)im;
            hmim[j] = (_Float16)(-im);
        }
        int n = n0 + lane_n;
        _Float16* r0 = g_B2t + (size_t)(2 * n)     * 512;
        _Float16* r1 = g_B2t + (size_t)(2 * n + 1) * 512;
        *reinterpret_cast<half4*>(r0 + k0 + kq)       = hre;
        *reinterpret_cast<half4*>(r0 + 256 + k0 + kq) = hmim;
        *reinterpret_cast<half4*>(r1 + k0 + kq)       = him;
        *reinterpret_cast<half4*>(r1 + 256 + k0 + kq) = hre;
        return;
    }
    if (bx < 1536) {                           // ---- xT[b][n] float2 (x^T)
        float (*lre)[33] = (float(*)[33])sbuf;
        float (*lim)[33] = (float(*)[33])(sbuf + 4224);
        int idx = bx - 512;
        int n0  = (idx >> 5) * 32;
        int b0  = (idx & 31) * 32;
        {
            int kk  = tid >> 3;
            int tx4 = (tid & 7) * 4;
            const floatx4 re4 = *reinterpret_cast<const floatx4*>(
                x_re + (size_t)(n0 + kk) * 1024 + b0 + tx4);
            const floatx4 im4 = *reinterpret_cast<const floatx4*>(
                x_im + (size_t)(n0 + kk) * 1024 + b0 + tx4);
#pragma unroll
            for (int j = 0; j < 4; ++j) {
                lre[kk][tx4 + j] = re4[j];
                lim[kk][tx4 + j] = im4[j];
            }
        }
        __syncthreads();
        int bb  = tid >> 3;
        int nn4 = (tid & 7) * 4;
        float2* dst = g_xT + (size_t)(b0 + bb) * 1024 + n0 + nn4;
        floatx4 w0, w1;
        w0[0] = lre[nn4 + 0][bb]; w0[1] = lim[nn4 + 0][bb];
        w0[2] = lre[nn4 + 1][bb]; w0[3] = lim[nn4 + 1][bb];
        w1[0] = lre[nn4 + 2][bb]; w1[1] = lim[nn4 + 2][bb];
        w1[2] = lre[nn4 + 3][bb]; w1[3] = lim[nn4 + 3][bb];
        *reinterpret_cast<floatx4*>(dst)     = w0;
        *reinterpret_cast<floatx4*>(dst + 2) = w1;
        return;
    }
    // ---- bx == 1536: V = DIF-FFT_2048(u~) * (1/2048), bit-reversed order ----
    float2* du = (float2*)sbuf;
    float*  twr = (float*)(sbuf + 16384);
    float*  twi = (float*)(sbuf + 20480);
#pragma unroll
    for (int r = 0; r < 4; ++r) {
        int k = tid + 256 * r;
        float ang = (float)k * TWN;
        float s, c;
        __sincosf(ang, &s, &c);
        twr[k] = c; twi[k] = -s;
    }
#pragma unroll
    for (int r = 0; r < 8; ++r) {
        int k = tid + 256 * r;
        float2 val;
        if (k < 1024)      { val.x = v_re[1023 + k]; val.y = v_im[1023 + k]; }
        else if (k == 1024){ val.x = 0.f; val.y = 0.f; }
        else               { val.x = v_re[k - 1025]; val.y = v_im[k - 1025]; }
        du[k] = val;
    }
    for (int s = 0; s < 11; ++s) {
        int lh = 10 - s, h = 1 << lh;
        __syncthreads();
#pragma unroll
        for (int r = 0; r < 4; ++r) {
            int i  = tid + 256 * r;
            int j  = i & (h - 1);
            int i0 = ((i >> lh) << (lh + 1)) | j;
            int i1 = i0 + h;
            float2 a = du[i0], b = du[i1];
            float dx = a.x - b.x, dy = a.y - b.y;
            int ti = j << s;
            float wr = twr[ti], wi = twi[ti];
            float2 s0; s0.x = a.x + b.x; s0.y = a.y + b.y;
            float2 d0; d0.x = dx * wr - dy * wi; d0.y = dx * wi + dy * wr;
            du[i0] = s0; du[i1] = d0;
        }
    }
    __syncthreads();
#pragma unroll
    for (int r = 0; r < 8; ++r) {
        int k = tid + 256 * r;
        float2 v = du[k];
        v.x *= (1.0f / 2048.0f); v.y *= (1.0f / 2048.0f);
        g_V[k] = v;
    }
}

// ---------------- FFT convolution v3: register-resident ----------------------
// 1024 blocks x 128 thr, 1 column each. 16 f2/thread; 4 LDS exchanges (dbuf).
#define PHYS(L) ((L) + ((L) >> 4))
__global__ __launch_bounds__(128) void fft_conv()
{
    __shared__ float2 ex[2][2176];     // PHYS(2047)=2174; dbuf 34.8KB

    const int t = threadIdx.x;         // 0..127
    const int b = blockIdx.x;
    const int q = t >> 3, u = t & 7;

    float2 e[16];

    auto tw = [](int expo) {
        float sn, cs;
        __sincosf((float)expo * TWN, &sn, &cs);
        float2 w; w.x = cs; w.y = -sn;      // W^expo = exp(-i*2pi*expo/2048)
        return w;
    };
    auto fwd = [](float2& A, float2& B, float2 w) {
        float2 a = A, c = B;
        float dx = a.x - c.x, dy = a.y - c.y;
        A.x = a.x + c.x; A.y = a.y + c.y;
        B.x = dx * w.x - dy * w.y;          // d * w
        B.y = dx * w.y + dy * w.x;
    };
    auto inv = [](float2& A, float2& B, float2 w) {
        float2 a = A, c = B;                // t1 = c * conj(w)
        float tx = c.x * w.x + c.y * w.y;
        float ty = c.y * w.x - c.x * w.y;
        A.x = a.x + tx; A.y = a.y + ty;
        B.x = a.x - tx; B.y = a.y - ty;
    };

    // ---- load L0: e[r] = x~[t + 128 r]; upper half zero ----
    const float2* src = g_xT + (size_t)b * 1024;
#pragma unroll
    for (int r = 0; r < 8; ++r) e[r] = src[t + 128 * r];
#pragma unroll
    for (int r = 8; r < 16; ++r) { e[r].x = 0.f; e[r].y = 0.f; }

    // ---- forward s=0..3 (register-local in L0) ----
#pragma unroll
    for (int r = 0; r < 8; ++r) fwd(e[r], e[r + 8], tw(t + 128 * r));          // s=0
#pragma unroll
    for (int r0 = 0; r0 < 4; ++r0) {                                           // s=1
        float2 w = tw((t + 128 * r0) << 1);
        fwd(e[r0], e[r0 + 4], w); fwd(e[r0 + 8], e[r0 + 12], w);
    }
#pragma unroll
    for (int r0 = 0; r0 < 2; ++r0) {                                           // s=2
        float2 w = tw((t + 128 * r0) << 2);
#pragma unroll
        for (int g4 = 0; g4 < 4; ++g4) fwd(e[g4 * 4 + r0], e[g4 * 4 + r0 + 2], w);
    }
    {                                                                          // s=3
        float2 w = tw(t << 3);
#pragma unroll
        for (int g2 = 0; g2 < 8; ++g2) fwd(e[g2 * 2], e[g2 * 2 + 1], w);
    }

    // ---- exchange 1: L0 -> L1 (f[k] = x[128 q + u + 8 k]) ----
#pragma unroll
    for (int r = 0; r < 16; ++r) { int L = 128 * r + t; ex[0][PHYS(L)] = e[r]; }
    __syncthreads();
#pragma unroll
    for (int k = 0; k < 16; ++k) { int L = 128 * q + u + 8 * k; e[k] = ex[0][PHYS(L)]; }

    // ---- forward s=4..7 (register-local in L1) ----
#pragma unroll
    for (int k = 0; k < 8; ++k) fwd(e[k], e[k + 8], tw((u + 8 * k) << 4));     // s=4
#pragma unroll
    for (int k0 = 0; k0 < 4; ++k0) {                                           // s=5
        float2 w = tw((u + 8 * k0) << 5);
        fwd(e[k0], e[k0 + 4], w); fwd(e[k0 + 8], e[k0 + 12], w);
    }
#pragma unroll
    for (int k0 = 0; k0 < 2; ++k0) {                                           // s=6
        float2 w = tw((u + 8 * k0) << 6);
#pragma unroll
        for (int g4 = 0; g4 < 4; ++g4) fwd(e[g4 * 4 + k0], e[g4 * 4 + k0 + 2], w);
    }
    {                                                                          // s=7
        float2 w = tw(u << 7);
#pragma unroll
        for (int g2 = 0; g2 < 8; ++g2) fwd(e[g2 * 2], e[g2 * 2 + 1], w);
    }

    // ---- exchange 2: L1 -> L2 (g[k] = x[16 t + k]) ----
#pragma unroll
    for (int k = 0; k < 16; ++k) { int L = 128 * q + u + 8 * k; ex[1][PHYS(L)] = e[k]; }
    __syncthreads();
#pragma unroll
    for (int k = 0; k < 16; ++k) { int L = 16 * t + k; e[k] = ex[1][PHYS(L)]; }

    // ---- forward s=8..10 (register-local in L2) ----
#pragma unroll
    for (int c = 0; c < 4; ++c) {                                              // s=8
        float2 w = tw(c << 8);
        fwd(e[c], e[c + 4], w); fwd(e[c + 8], e[c + 12], w);
    }
#pragma unroll
    for (int g4 = 0; g4 < 4; ++g4) {                                           // s=9
        fwd(e[g4 * 4], e[g4 * 4 + 2], (float2){1.f, 0.f});
        float2& A = e[g4 * 4 + 1]; float2& B = e[g4 * 4 + 3];
        float2 a = A, c2 = B;
        float dx = a.x - c2.x, dy = a.y - c2.y;
        A.x = a.x + c2.x; A.y = a.y + c2.y;
        B.x = dy; B.y = -dx;
    }
#pragma unroll
    for (int g2 = 0; g2 < 8; ++g2) {                                           // s=10
        float2 a = e[g2 * 2], c2 = e[g2 * 2 + 1];
        e[g2 * 2].x     = a.x + c2.x; e[g2 * 2].y     = a.y + c2.y;
        e[g2 * 2 + 1].x = a.x - c2.x; e[g2 * 2 + 1].y = a.y - c2.y;
    }

    // ---- pointwise * V (bit-reversed domain; V pre-scaled 1/2048) ----
#pragma unroll
    for (int k = 0; k < 16; ++k) {
        float2 v = g_V[16 * t + k];
        float2 a = e[k];
        e[k].x = a.x * v.x - a.y * v.y;
        e[k].y = a.x * v.y + a.y * v.x;
    }

    // ---- inverse ss=0..2 (register-local in L2) ----
#pragma unroll
    for (int g2 = 0; g2 < 8; ++g2) {                                           // ss=0
        float2 a = e[g2 * 2], c2 = e[g2 * 2 + 1];
        e[g2 * 2].x     = a.x + c2.x; e[g2 * 2].y     = a.y + c2.y;
        e[g2 * 2 + 1].x = a.x - c2.x; e[g2 * 2 + 1].y = a.y - c2.y;
    }
#pragma unroll
    for (int g4 = 0; g4 < 4; ++g4) {                                           // ss=1
        inv(e[g4 * 4], e[g4 * 4 + 2], (float2){1.f, 0.f});
        // c=1: conj(w)= (0,1): t1 = (-c.y, c.x)
        float2& A = e[g4 * 4 + 1]; float2& B = e[g4 * 4 + 3];
        float2 a = A, c2 = B;
        float tx = -c2.y, ty = c2.x;
        A.x = a.x + tx; A.y = a.y + ty;
        B.x = a.x - tx; B.y = a.y - ty;
    }
#pragma unroll
    for (int c = 0; c < 4; ++c) {                                              // ss=2
        float2 w = tw(c << 8);
        inv(e[c], e[c + 4], w); inv(e[c + 8], e[c + 12], w);
    }

    // ---- exchange 3: L2 -> L1 ----
#pragma unroll
    for (int k = 0; k < 16; ++k) { int L = 16 * t + k; ex[0][PHYS(L)] = e[k]; }
    __syncthreads();
#pragma unroll
    for (int k = 0; k < 16; ++k) { int L = 128 * q + u + 8 * k; e[k] = ex[0][PHYS(L)]; }

    // ---- inverse ss=3..6 (register-local in L1) ----
    {                                                                          // ss=3
        float2 w = tw(u << 7);
#pragma unroll
        for (int g2 = 0; g2 < 8; ++g2) inv(e[g2 * 2], e[g2 * 2 + 1], w);
    }
#pragma unroll
    for (int k0 = 0; k0 < 2; ++k0) {                                           // ss=4
        float2 w = tw((u + 8 * k0) << 6);
#pragma unroll
        for (int g4 = 0; g4 < 4; ++g4) inv(e[g4 * 4 + k0], e[g4 * 4 + k0 + 2], w);
    }
#pragma unroll
    for (int k0 = 0; k0 < 4; ++k0) {                                           // ss=5
        float2 w = tw((u + 8 * k0) << 5);
        inv(e[k0], e[k0 + 4], w); inv(e[k0 + 8], e[k0 + 12], w);
    }
#pragma unroll
    for (int k = 0; k < 8; ++k) inv(e[k], e[k + 8], tw((u + 8 * k) << 4));     // ss=6

    // ---- exchange 4: L1 -> L0 ----
#pragma unroll
    for (int k = 0; k < 16; ++k) { int L = 128 * q + u + 8 * k; ex[1][PHYS(L)] = e[k]; }
    __syncthreads();
#pragma unroll
    for (int r = 0; r < 16; ++r) { int L = 128 * r + t; e[r] = ex[1][PHYS(L)]; }

    // ---- inverse ss=7..10 (register-local in L0) ----
    {                                                                          // ss=7
        float2 w = tw(t << 3);
#pragma unroll
        for (int g2 = 0; g2 < 8; ++g2) inv(e[g2 * 2], e[g2 * 2 + 1], w);
    }
#pragma unroll
    for (int r0 = 0; r0 < 2; ++r0) {                                           // ss=8
        float2 w = tw((t + 128 * r0) << 2);
#pragma unroll
        for (int g4 = 0; g4 < 4; ++g4) inv(e[g4 * 4 + r0], e[g4 * 4 + r0 + 2], w);
    }
#pragma unroll
    for (int r0 = 0; r0 < 4; ++r0) {                                           // ss=9
        float2 w = tw((t + 128 * r0) << 1);
        inv(e[r0], e[r0 + 4], w); inv(e[r0 + 8], e[r0 + 12], w);
    }
    // ss=10: only lower outputs needed: e[r] = a + b*conj(w)
    float2* dst = g_convT + (size_t)b * 1024;
#pragma unroll
    for (int r = 0; r < 8; ++r) {
        float2 w = tw(t + 128 * r);
        float2 a = e[r], c2 = e[r + 8];
        float tx = c2.x * w.x + c2.y * w.y;
        float ty = c2.y * w.x - c2.x * w.y;
        float2 o; o.x = a.x + tx; o.y = a.y + ty;
        dst[t + 128 * r] = o;
    }
}

// ---------------- W2@y GEMM (K=512) + fused conv-add + soft-threshold --------
// R13 structure; epilogue LDS-stages the conv tile (coalesced) before use.
__global__ __launch_bounds__(256, 2) void gemm_w2y(float* __restrict__ out,
                                                   int out_n)
{
    __shared__ __align__(16) _Float16 As[2 * 4 * 64 * 32];
    __shared__ __align__(16) _Float16 Bs[2 * 4 * 64 * 32];

    const int tid  = threadIdx.x;
    const int lane = tid & 63;
    const int w    = tid >> 6;
    const int wm   = w >> 1;
    const int wn   = w & 1;

    const int bid = blockIdx.x;
    const int xcd = bid & 7;
    const int t   = bid >> 3;
    const int mi0 = ((xcd & 1) * 8 + (t & 7)) * 64;
    const int ni0 = ((xcd >> 1) * 8 + (t >> 3)) * 64;

    floatx4 acc[2][2];
#pragma unroll
    for (int a = 0; a < 2; ++a)
#pragma unroll
        for (int b = 0; b < 2; ++b) acc[a][b] = (floatx4)0.0f;

    const int rS = tid >> 2;
    const int jS = tid & 3;
    const int s0 = ((rS & 15) >> 1) & 3;
    char* asW = (char*)As + rS * 64 + ((jS ^ s0) * 16);
    char* bsW = (char*)Bs + rS * 64 + ((jS ^ s0) * 16);
    const _Float16* gA = g_A2  + (size_t)(mi0 + rS) * 512 + jS * 8;
    const _Float16* gB = g_B2t + (size_t)(ni0 + rS) * 512 + jS * 8;

    const int rowA = lane & 15;
    const int q    = lane >> 4;
    const int coff = (q ^ ((rowA >> 1) & 3)) * 16;

    const int NIT = 512 / 128;           // 4

    half8 sA[2][4], sB[2][4];
    {
        half8 tA[4], tB[4];
#pragma unroll
        for (int ks = 0; ks < 4; ++ks) {
            tA[ks] = *reinterpret_cast<const half8*>(gA + ks * 32);
            tB[ks] = *reinterpret_cast<const half8*>(gB + ks * 32);
        }
#pragma unroll
        for (int ks = 0; ks < 4; ++ks) {
            sA[1][ks] = *reinterpret_cast<const half8*>(gA + 128 + ks * 32);
            sB[1][ks] = *reinterpret_cast<const half8*>(gB + 128 + ks * 32);
        }
#pragma unroll
        for (int ks = 0; ks < 4; ++ks) {
            *reinterpret_cast<half8*>(asW + ks * 4096) = tA[ks];
            *reinterpret_cast<half8*>(bsW + ks * 4096) = tB[ks];
        }
    }
    __syncthreads();

#pragma unroll 2
    for (int kt = 0; kt < NIT; ++kt) {
        const int cur = kt & 1;
        const int nxt = cur ^ 1;
        if (kt + 2 < NIT) {
            const _Float16* ga = gA + (size_t)(kt + 2) * 128;
            const _Float16* gb = gB + (size_t)(kt + 2) * 128;
#pragma unroll
            for (int ks = 0; ks < 4; ++ks) {
                sA[cur][ks] = *reinterpret_cast<const half8*>(ga + ks * 32);
                sB[cur][ks] = *reinterpret_cast<const half8*>(gb + ks * 32);
            }
        }
        const char* Ab = (const char*)As + cur * 16384;
        const char* Bb = (const char*)Bs + cur * 16384;
#pragma unroll
        for (int ks = 0; ks < 4; ++ks) {
            half8 af[2], bf[2];
#pragma unroll
            for (int mi = 0; mi < 2; ++mi) {
                int r = wm * 32 + mi * 16 + rowA;
                af[mi] = *reinterpret_cast<const half8*>(Ab + ks * 4096 + r * 64 + coff);
            }
#pragma unroll
            for (int ni = 0; ni < 2; ++ni) {
                int r = wn * 32 + ni * 16 + rowA;
                bf[ni] = *reinterpret_cast<const half8*>(Bb + ks * 4096 + r * 64 + coff);
            }
#pragma unroll
            for (int mi = 0; mi < 2; ++mi)
#pragma unroll
                for (int ni = 0; ni < 2; ++ni)
                    acc[mi][ni] = __builtin_amdgcn_mfma_f32_16x16x32_f16(
                        af[mi], bf[ni], acc[mi][ni], 0, 0, 0);
        }
        if (kt + 1 < NIT) {
            char* aw = asW + nxt * 16384;
            char* bw = bsW + nxt * 16384;
#pragma unroll
            for (int ks = 0; ks < 4; ++ks) {
                *reinterpret_cast<half8*>(aw + ks * 4096) = sA[nxt][ks];
                *reinterpret_cast<half8*>(bw + ks * 4096) = sB[nxt][ks];
            }
        }
        __syncthreads();
    }

    // ---- stage conv tile (coalesced) into LDS: Lc[32][64], stride 66 --------
    float2* Lc = (float2*)As;            // K-loop done (barrier passed), As free
    {
        const int bl  = tid >> 3;        // 0..31
        const int il8 = (tid & 7) * 8;   // 0..56
        const float2* gsc = g_convT + (size_t)((ni0 >> 1) + bl) * 1024 + mi0 + il8;
#pragma unroll
        for (int j = 0; j < 8; j += 2) {
            floatx4 v = *reinterpret_cast<const floatx4*>(gsc + j);
            *reinterpret_cast<floatx4*>(Lc + bl * 66 + il8 + j) = v;
        }
    }
    __syncthreads();

    // epilogue: lane pair (even,odd) = (Re,Im); add conv, threshold, store Re.
    const int colL  = lane & 15;
    const int rquad = (lane >> 4) * 4;
#pragma unroll
    for (int mi = 0; mi < 2; ++mi)
#pragma unroll
        for (int ni = 0; ni < 2; ++ni)
#pragma unroll
            for (int r = 0; r < 4; ++r) {
                float c = acc[mi][ni][r];
                float p = __shfl_xor(c, 1, 64);
                if (!(colL & 1)) {
                    int bl2 = (wn * 32 + ni * 16 + colL) >> 1;   // 0..31
                    int il2 = wm * 32 + mi * 16 + rquad + r;     // 0..63
                    float2 cv = Lc[bl2 * 66 + il2];
                    float re = c + cv.x;
                    float im = p + cv.y;
                    float mag = sqrtf(re * re + im * im);
                    float s = fmaxf(mag - BETA_F, 0.0f) / fmaxf(mag, EPS_F);
                    int row  = mi0 + il2;
                    int bcol = (ni0 >> 1) + bl2;
                    size_t o = (size_t)row * 1024 + bcol;
                    if (o < (size_t)out_n) out[o] = re * s;
                }
            }
}

// ---------------- launcher ---------------------------------------------------
extern "C" void kernel_launch(void* const* d_in, const int* in_sizes, int n_in,
                              void* d_out, int out_size, void* d_ws, size_t ws_size,
                              hipStream_t stream) {
    (void)d_ws; (void)ws_size; (void)in_sizes; (void)n_in;
    const float* v_re  = (const float*)d_in[0];
    const float* v_im  = (const float*)d_in[1];
    const float* W2_re = (const float*)d_in[2];
    const float* W2_im = (const float*)d_in[3];
    const float* x_re  = (const float*)d_in[4];
    const float* x_im  = (const float*)d_in[5];
    const float* y_re  = (const float*)d_in[6];
    const float* y_im  = (const float*)d_in[7];
    float* out = (float*)d_out;

    build_all<<<1537, 256, 0, stream>>>(v_re, v_im, W2_re, W2_im,
                                        x_re, x_im, y_re, y_im);
    fft_conv<<<1024, 128, 0, stream>>>();
    gemm_w2y<<<512, 256, 0, stream>>>(out, out_size);
}